// Round 2
// baseline (206.558 us; speedup 1.0000x reference)
//
#include <hip/hip_runtime.h>
#include <hip/hip_bf16.h>

#define NE 8192
#define BATCH 64
#define NNZT (NE * 32)
#define KSPLIT 8
#define KCH (NE / KSPLIT)  // 1024 k per wave

typedef float f32x4 __attribute__((ext_vector_type(4)));
typedef short s16x8 __attribute__((ext_vector_type(8)));

__device__ __forceinline__ unsigned short f2bf(float f) {
  unsigned u = __builtin_bit_cast(unsigned, f);
  return (unsigned short)((u + 0x7FFFu + ((u >> 16) & 1u)) >> 16);  // RNE
}

__device__ __forceinline__ s16x8 cvt8(f32x4 a, f32x4 b) {
  s16x8 r;
#pragma unroll
  for (int j = 0; j < 4; ++j) {
    r[j] = (short)f2bf(a[j]);
    r[j + 4] = (short)f2bf(b[j]);
  }
  return r;
}

// x fp32 [64][8192] -> bf16 (as ushort)
__global__ void k_convert_x(const float* __restrict__ x, unsigned short* __restrict__ xb) {
  int i = (blockIdx.x * 256 + threadIdx.x) * 4;
  float4 v = *reinterpret_cast<const float4*>(x + i);
  *reinterpret_cast<ushort4*>(xb + i) =
      make_ushort4(f2bf(v.x), f2bf(v.y), f2bf(v.z), f2bf(v.w));
}

__global__ void k_zero(float* __restrict__ p) {
  int i = (blockIdx.x * 256 + threadIdx.x) * 4;
  *reinterpret_cast<float4*>(p + i) = make_float4(0.f, 0.f, 0.f, 0.f);
}

// h = x @ W^T stored transposed ht[i][b]. Barrier-free register streaming:
// wave gw -> i-block = gw>>3 (16 rows of W), k-quarter kq = gw&7 (1024 k).
// B-frag straight from global W (fp32 -> bf16 in reg); A-frag from L2-resident
// bf16 x. Partial K-sums combined via atomicAdd into zeroed ht.
__global__ __launch_bounds__(256, 4) void k_dense(const unsigned short* __restrict__ xb,
                                                  const float* __restrict__ W,
                                                  float* __restrict__ ht) {
  const int lane = threadIdx.x & 63;
  const int gw = blockIdx.x * 4 + (threadIdx.x >> 6);
  const int i0 = (gw >> 3) * 16;
  const int kq = gw & 7;
  const int row16 = lane & 15;
  const int k8 = (lane >> 4) * 8;

  const float* wp = W + (size_t)(i0 + row16) * NE + kq * KCH + k8;
  const unsigned short* xp = xb + (size_t)row16 * NE + kq * KCH + k8;

  f32x4 acc0 = {0.f, 0.f, 0.f, 0.f};
  f32x4 acc1 = {0.f, 0.f, 0.f, 0.f};
  f32x4 acc2 = {0.f, 0.f, 0.f, 0.f};
  f32x4 acc3 = {0.f, 0.f, 0.f, 0.f};

#pragma unroll 2
  for (int k = 0; k < KCH; k += 32) {
    f32x4 w0 = *reinterpret_cast<const f32x4*>(wp + k);
    f32x4 w1 = *reinterpret_cast<const f32x4*>(wp + k + 4);
    s16x8 a0 = *reinterpret_cast<const s16x8*>(xp + k);
    s16x8 a1 = *reinterpret_cast<const s16x8*>(xp + (size_t)16 * NE + k);
    s16x8 a2 = *reinterpret_cast<const s16x8*>(xp + (size_t)32 * NE + k);
    s16x8 a3 = *reinterpret_cast<const s16x8*>(xp + (size_t)48 * NE + k);
    s16x8 bfr = cvt8(w0, w1);
    acc0 = __builtin_amdgcn_mfma_f32_16x16x32_bf16(a0, bfr, acc0, 0, 0, 0);
    acc1 = __builtin_amdgcn_mfma_f32_16x16x32_bf16(a1, bfr, acc1, 0, 0, 0);
    acc2 = __builtin_amdgcn_mfma_f32_16x16x32_bf16(a2, bfr, acc2, 0, 0, 0);
    acc3 = __builtin_amdgcn_mfma_f32_16x16x32_bf16(a3, bfr, acc3, 0, 0, 0);
  }

  // C/D: i = i0 + (lane&15), b = g*16 + (lane>>4)*4 + j
  float* hp = ht + (size_t)(i0 + row16) * BATCH + (lane >> 4) * 4;
#pragma unroll
  for (int j = 0; j < 4; ++j) atomicAdd(hp + j, acc0[j]);
#pragma unroll
  for (int j = 0; j < 4; ++j) atomicAdd(hp + 16 + j, acc1[j]);
#pragma unroll
  for (int j = 0; j < 4; ++j) atomicAdd(hp + 32 + j, acc2[j]);
#pragma unroll
  for (int j = 0; j < 4; ++j) atomicAdd(hp + 48 + j, acc3[j]);
}

// out_t[c][b] += ht[r][b] * w  for each nnz. One wave per nnz-chunk, lane = b.
__global__ void k_scatter(const float* __restrict__ ht, const float* __restrict__ sw,
                          const int* __restrict__ rows, const int* __restrict__ cols,
                          float* __restrict__ out_t) {
  const int w = (blockIdx.x * 256 + threadIdx.x) >> 6;  // 0..4095
  const int lane = threadIdx.x & 63;
  const int n0 = w * (NNZT / 4096);                     // 64 nnz per wave
#pragma unroll 4
  for (int n = n0; n < n0 + (NNZT / 4096); ++n) {
    const int r = rows[n];
    const int c = cols[n];
    const float wv = sw[n];
    atomicAdd(out_t + (size_t)c * BATCH + lane, ht[(size_t)r * BATCH + lane] * wv);
  }
}

// out[b][j] = leaky(out_t[j][b]) via LDS transpose. Grid 128 (j-tiles of 64).
__global__ void k_final(const float* __restrict__ out_t, float* __restrict__ out) {
  __shared__ float tile[64][65];
  const int t = threadIdx.x;
  const int j0 = blockIdx.x * 64;
  {
    const int jl = t >> 2, b0 = (t & 3) * 16;
    const float* src = out_t + (size_t)(j0 + jl) * BATCH + b0;
#pragma unroll
    for (int e = 0; e < 16; e += 4) {
      float4 v = *reinterpret_cast<const float4*>(src + e);
      tile[jl][b0 + e + 0] = v.x;
      tile[jl][b0 + e + 1] = v.y;
      tile[jl][b0 + e + 2] = v.z;
      tile[jl][b0 + e + 3] = v.w;
    }
  }
  __syncthreads();
  {
    const int bl = t >> 2, js = (t & 3) * 16;
    float* dst = out + (size_t)bl * NE + j0 + js;
#pragma unroll
    for (int e = 0; e < 16; e += 4) {
      float a0 = tile[js + e + 0][bl];
      float a1 = tile[js + e + 1][bl];
      float a2 = tile[js + e + 2][bl];
      float a3 = tile[js + e + 3][bl];
      float4 v;
      v.x = a0 >= 0.f ? a0 : 0.001f * a0;
      v.y = a1 >= 0.f ? a1 : 0.001f * a1;
      v.z = a2 >= 0.f ? a2 : 0.001f * a2;
      v.w = a3 >= 0.f ? a3 : 0.001f * a3;
      *reinterpret_cast<float4*>(dst + e) = v;
    }
  }
}

extern "C" void kernel_launch(void* const* d_in, const int* in_sizes, int n_in,
                              void* d_out, int out_size, void* d_ws, size_t ws_size,
                              hipStream_t stream) {
  const float* x = (const float*)d_in[0];
  const float* W = (const float*)d_in[1];
  const float* sw = (const float*)d_in[2];
  const int* idx = (const int*)d_in[3];  // [2][NNZ]: rows then cols
  float* out = (float*)d_out;

  char* ws = (char*)d_ws;
  float* ht = (float*)ws;                                   // 2 MB: ht[8192][64]
  float* out_t = (float*)(ws + (2 << 20));                  // 2 MB: out_t[8192][64]
  unsigned short* xbf = (unsigned short*)(ws + (4 << 20));  // 1 MB: x in bf16

  k_convert_x<<<512, 256, 0, stream>>>(x, xbf);
  k_zero<<<1024, 256, 0, stream>>>((float*)ws);  // zero ht + out_t (4 MB)
  k_dense<<<1024, 256, 0, stream>>>(xbf, W, ht);
  k_scatter<<<1024, 256, 0, stream>>>(ht, sw, idx, idx + NNZT, out_t);
  k_final<<<128, 256, 0, stream>>>(out_t, out);
}

// Round 3
// 167.228 us; speedup vs baseline: 1.2352x; 1.2352x over previous
//
#include <hip/hip_runtime.h>
#include <hip/hip_bf16.h>

#define NE 8192
#define BATCH 64
#define NNZT (NE * 32)
#define KSPLIT 8
#define KCH (NE / KSPLIT)  // 1024 k per block
#define BK 32              // k per step
#define NSTEP (KCH / BK)   // 32 steps
#define TN 64              // W rows per block

typedef float f32x4 __attribute__((ext_vector_type(4)));
typedef short s16x8 __attribute__((ext_vector_type(8)));

__device__ __forceinline__ unsigned short f2bf(float f) {
  unsigned u = __builtin_bit_cast(unsigned, f);
  return (unsigned short)((u + 0x7FFFu + ((u >> 16) & 1u)) >> 16);  // RNE
}

__device__ __forceinline__ s16x8 cvt8(f32x4 a, f32x4 b) {
  s16x8 r;
#pragma unroll
  for (int j = 0; j < 4; ++j) {
    r[j] = (short)f2bf(a[j]);
    r[j + 4] = (short)f2bf(b[j]);
  }
  return r;
}

__device__ __forceinline__ void gld16(const void* g, void* l) {
  __builtin_amdgcn_global_load_lds(
      (const __attribute__((address_space(1))) unsigned int*)g,
      (__attribute__((address_space(3))) unsigned int*)l, 16, 0, 0);
}

// x fp32 [64][8192] -> bf16 (as ushort)
__global__ void k_convert_x(const float* __restrict__ x, unsigned short* __restrict__ xb) {
  int i = (blockIdx.x * 256 + threadIdx.x) * 4;
  float4 v = *reinterpret_cast<const float4*>(x + i);
  *reinterpret_cast<ushort4*>(xb + i) =
      make_ushort4(f2bf(v.x), f2bf(v.y), f2bf(v.z), f2bf(v.w));
}

__global__ void k_zero(float* __restrict__ p) {
  int i = (blockIdx.x * 256 + threadIdx.x) * 4;
  *reinterpret_cast<float4*>(p + i) = make_float4(0.f, 0.f, 0.f, 0.f);
}

// h = x @ W^T stored transposed ht[i][b], partial-K via atomicAdd.
// Block: 4 waves, TN=64 W rows, KCH=1024. Double-buffered global_load_lds
// staging, one barrier per BK=32 step (implicit vmcnt(0) drain = the wait).
// W LDS tile [64 rows][128 B] XOR-swizzled (byte ^= (row&7)<<4) via
// pre-swizzled global source (linear DMA dest) + swizzled ds_read.
// x LDS tile stored k-chunk-major [4 kchunk][64 row][16 B] -> 2-way reads.
__global__ __launch_bounds__(256, 4) void k_dense(const unsigned short* __restrict__ xb,
                                                  const float* __restrict__ W,
                                                  float* __restrict__ ht) {
  __shared__ __align__(16) char smem[2 * 8192 + 2 * 4096];
  char* const Wb0 = smem;          // two 8 KB W buffers
  char* const Xb0 = smem + 16384;  // two 4 KB x buffers

  const int tid = threadIdx.x;
  const int kq = blockIdx.x & (KSPLIT - 1);
  const int i0 = (blockIdx.x >> 3) * TN;
  const int k0 = kq * KCH;

  // ---- staging (per step: 2 W instrs + 1 x instr, all linear DMA dests) ----
  const int wr = tid >> 3;                              // W tile row 0..31 (+32 for instr1)
  const int wcs = ((tid & 7) * 16) ^ ((wr & 7) << 4);   // inverse-swizzled source chunk
  const char* wg0 = (const char*)W + ((size_t)(i0 + wr) * NE + k0) * 4 + wcs;
  const char* wg1 = wg0 + (size_t)32 * NE * 4;
  // x: thread t stages x[row = t&63][k0 + s*32 + (t>>6)*8 .. +8] at dest t*16
  const char* xg = (const char*)xb + ((size_t)(tid & 63) * NE + k0 + (tid >> 6) * 8) * 2;
  const int dst16 = tid * 16;

  // ---- fragment read offsets (loop-invariant) ----
  const int l = tid & 63, wave = tid >> 6;
  const int r16 = l & 15, q = l >> 4;
  const int rB = wave * 16 + r16;  // W tile row this lane reads
  const int bofs0 = rB * 128 + ((q * 32) ^ ((rB & 7) << 4));
  const int bofs1 = rB * 128 + ((q * 32 + 16) ^ ((rB & 7) << 4));
  const int aofs = q * 1024 + r16 * 16;  // + g*256 for b-group g

  f32x4 acc[4] = {};

  // prologue: stage step 0 into buffer 0
  gld16(wg0, Wb0 + dst16);
  gld16(wg1, Wb0 + 4096 + dst16);
  gld16(xg, Xb0 + dst16);
  __syncthreads();

  for (int s = 0; s < NSTEP; ++s) {
    const int cur = s & 1;
    if (s + 1 < NSTEP) {  // stage next tile into other buffer (overlaps with MFMA below)
      const int nxt = cur ^ 1;
      const char* wgn = wg0 + (size_t)(s + 1) * (BK * 4);
      gld16(wgn, Wb0 + nxt * 8192 + dst16);
      gld16(wgn + (size_t)32 * NE * 4, Wb0 + nxt * 8192 + 4096 + dst16);
      gld16(xg + (size_t)(s + 1) * (BK * 2), Xb0 + nxt * 4096 + dst16);
    }
    const char* wb = Wb0 + cur * 8192;
    const char* xl = Xb0 + cur * 4096;
    f32x4 w0 = *(const f32x4*)(wb + bofs0);
    f32x4 w1 = *(const f32x4*)(wb + bofs1);
    s16x8 bfr = cvt8(w0, w1);
#pragma unroll
    for (int g = 0; g < 4; ++g) {
      s16x8 a = *(const s16x8*)(xl + aofs + g * 256);
      acc[g] = __builtin_amdgcn_mfma_f32_16x16x32_bf16(a, bfr, acc[g], 0, 0, 0);
    }
    __syncthreads();  // implicit vmcnt(0): next tile landed; cur buffer reusable
  }

  // C/D: i = i0 + rB (col = lane&15 within wave's 16 rows), b = g*16 + q*4 + j
  float* hp = ht + (size_t)(i0 + rB) * BATCH + q * 4;
#pragma unroll
  for (int g = 0; g < 4; ++g)
#pragma unroll
    for (int j = 0; j < 4; ++j)
      atomicAdd(hp + g * 16 + j, acc[g][j]);
}

// out_t[c][b] += ht[r][b] * w  for each nnz. One wave per nnz-chunk, lane = b.
__global__ void k_scatter(const float* __restrict__ ht, const float* __restrict__ sw,
                          const int* __restrict__ rows, const int* __restrict__ cols,
                          float* __restrict__ out_t) {
  const int w = (blockIdx.x * 256 + threadIdx.x) >> 6;  // 0..4095
  const int lane = threadIdx.x & 63;
  const int n0 = w * (NNZT / 4096);                     // 64 nnz per wave
#pragma unroll 4
  for (int n = n0; n < n0 + (NNZT / 4096); ++n) {
    const int r = rows[n];
    const int c = cols[n];
    const float wv = sw[n];
    atomicAdd(out_t + (size_t)c * BATCH + lane, ht[(size_t)r * BATCH + lane] * wv);
  }
}

// out[b][j] = leaky(out_t[j][b]) via LDS transpose. Grid 128 (j-tiles of 64).
__global__ void k_final(const float* __restrict__ out_t, float* __restrict__ out) {
  __shared__ float tile[64][65];
  const int t = threadIdx.x;
  const int j0 = blockIdx.x * 64;
  {
    const int jl = t >> 2, b0 = (t & 3) * 16;
    const float* src = out_t + (size_t)(j0 + jl) * BATCH + b0;
#pragma unroll
    for (int e = 0; e < 16; e += 4) {
      float4 v = *reinterpret_cast<const float4*>(src + e);
      tile[jl][b0 + e + 0] = v.x;
      tile[jl][b0 + e + 1] = v.y;
      tile[jl][b0 + e + 2] = v.z;
      tile[jl][b0 + e + 3] = v.w;
    }
  }
  __syncthreads();
  {
    const int bl = t >> 2, js = (t & 3) * 16;
    float* dst = out + (size_t)bl * NE + j0 + js;
#pragma unroll
    for (int e = 0; e < 16; e += 4) {
      float a0 = tile[js + e + 0][bl];
      float a1 = tile[js + e + 1][bl];
      float a2 = tile[js + e + 2][bl];
      float a3 = tile[js + e + 3][bl];
      float4 v;
      v.x = a0 >= 0.f ? a0 : 0.001f * a0;
      v.y = a1 >= 0.f ? a1 : 0.001f * a1;
      v.z = a2 >= 0.f ? a2 : 0.001f * a2;
      v.w = a3 >= 0.f ? a3 : 0.001f * a3;
      *reinterpret_cast<float4*>(dst + e) = v;
    }
  }
}

extern "C" void kernel_launch(void* const* d_in, const int* in_sizes, int n_in,
                              void* d_out, int out_size, void* d_ws, size_t ws_size,
                              hipStream_t stream) {
  const float* x = (const float*)d_in[0];
  const float* W = (const float*)d_in[1];
  const float* sw = (const float*)d_in[2];
  const int* idx = (const int*)d_in[3];  // [2][NNZ]: rows then cols (int32 from harness)
  float* out = (float*)d_out;

  char* ws = (char*)d_ws;
  float* ht = (float*)ws;                                   // 2 MB: ht[8192][64]
  float* out_t = (float*)(ws + (2 << 20));                  // 2 MB: out_t[8192][64]
  unsigned short* xbf = (unsigned short*)(ws + (4 << 20));  // 1 MB: x in bf16

  k_convert_x<<<512, 256, 0, stream>>>(x, xbf);
  k_zero<<<1024, 256, 0, stream>>>((float*)ws);  // zero ht + out_t (4 MB)
  k_dense<<<1024, 256, 0, stream>>>(xbf, W, ht);
  k_scatter<<<1024, 256, 0, stream>>>(ht, sw, idx, idx + NNZT, out_t);
  k_final<<<128, 256, 0, stream>>>(out_t, out);
}

// Round 4
// 154.320 us; speedup vs baseline: 1.3385x; 1.0836x over previous
//
#include <hip/hip_runtime.h>
#include <hip/hip_bf16.h>

#define NE 8192
#define BATCH 64
#define NNZT (NE * 32)
#define KSPLIT 8
#define KCH (NE / KSPLIT)  // 1024 k per block
#define BK 32              // k per step
#define NSTEP (KCH / BK)   // 32 steps
#define TN 64              // W rows per block

typedef float f32x4 __attribute__((ext_vector_type(4)));
typedef short s16x8 __attribute__((ext_vector_type(8)));

__device__ __forceinline__ unsigned short f2bf(float f) {
  unsigned u = __builtin_bit_cast(unsigned, f);
  return (unsigned short)((u + 0x7FFFu + ((u >> 16) & 1u)) >> 16);  // RNE
}

__device__ __forceinline__ s16x8 cvt8(f32x4 a, f32x4 b) {
  s16x8 r;
#pragma unroll
  for (int j = 0; j < 4; ++j) {
    r[j] = (short)f2bf(a[j]);
    r[j + 4] = (short)f2bf(b[j]);
  }
  return r;
}

__device__ __forceinline__ void gld16(const void* g, void* l) {
  __builtin_amdgcn_global_load_lds(
      (const __attribute__((address_space(1))) unsigned int*)g,
      (__attribute__((address_space(3))) unsigned int*)l, 16, 0, 0);
}

// x fp32 [64][8192] -> bf16 (as ushort)
__global__ void k_convert_x(const float* __restrict__ x, unsigned short* __restrict__ xb) {
  int i = (blockIdx.x * 256 + threadIdx.x) * 4;
  float4 v = *reinterpret_cast<const float4*>(x + i);
  *reinterpret_cast<ushort4*>(xb + i) =
      make_ushort4(f2bf(v.x), f2bf(v.y), f2bf(v.z), f2bf(v.w));
}

__global__ void k_zero(float* __restrict__ p) {
  int i = (blockIdx.x * 256 + threadIdx.x) * 4;
  *reinterpret_cast<float4*>(p + i) = make_float4(0.f, 0.f, 0.f, 0.f);
}

// h = x @ W^T stored transposed ht[i][b], partial-K via atomicAdd.
// Depth-3 counted-vmcnt pipeline (T3/T4): 4 LDS buffers, per step 3
// global_load_lds instrs/wave; top-of-iter wait is vmcnt(6) (step-s landed,
// s+1/s+2 stay in flight) — never vmcnt(0) in the main loop.
// W LDS tile [64 rows][128 B] XOR-swizzled (byte ^= (row&7)<<4) via
// pre-swizzled global source (linear DMA dest) + swizzled ds_read.
// x LDS tile k-chunk-major [4 kchunk][64 row][16 B] -> conflict-free reads.
__global__ __launch_bounds__(256, 3) void k_dense(const unsigned short* __restrict__ xb,
                                                  const float* __restrict__ W,
                                                  float* __restrict__ ht) {
  __shared__ __align__(16) char smem[4 * 8192 + 4 * 4096];  // 48 KB
  char* const Wb0 = smem;          // four 8 KB W buffers
  char* const Xb0 = smem + 32768;  // four 4 KB x buffers

  const int tid = threadIdx.x;
  const int kq = blockIdx.x & (KSPLIT - 1);
  const int i0 = (blockIdx.x >> 3) * TN;
  const int k0 = kq * KCH;

  // ---- staging addresses (per step: 2 W instrs + 1 x instr per wave) ----
  const int wr = tid >> 3;                             // W tile row 0..31 (+32 for instr1)
  const int wcs = ((tid & 7) * 16) ^ ((wr & 7) << 4);  // inverse-swizzled source chunk
  const char* wg0 = (const char*)W + ((size_t)(i0 + wr) * NE + k0) * 4 + wcs;
  const char* xg = (const char*)xb + ((size_t)(tid & 63) * NE + k0 + (tid >> 6) * 8) * 2;
  const int dst16 = tid * 16;

  // ---- fragment read offsets (loop-invariant) ----
  const int l = tid & 63, wave = tid >> 6;
  const int r16 = l & 15, q = l >> 4;
  const int rB = wave * 16 + r16;  // W tile row this lane reads
  const int bofs0 = rB * 128 + ((q * 32) ^ ((rB & 7) << 4));
  const int bofs1 = rB * 128 + ((q * 32 + 16) ^ ((rB & 7) << 4));
  const int aofs = q * 1024 + r16 * 16;  // + g*256 for b-group g

  f32x4 acc[4] = {};

#define STAGE(s)                                                      \
  do {                                                                \
    char* wb_ = Wb0 + ((s) & 3) * 8192;                               \
    char* xb_ = Xb0 + ((s) & 3) * 4096;                               \
    const char* wgn_ = wg0 + (size_t)(s) * (BK * 4);                  \
    gld16(wgn_, wb_ + dst16);                                         \
    gld16(wgn_ + (size_t)32 * NE * 4, wb_ + 4096 + dst16);            \
    gld16(xg + (size_t)(s) * (BK * 2), xb_ + dst16);                  \
  } while (0)

  STAGE(0);
  STAGE(1);
  STAGE(2);

  for (int s = 0; s < NSTEP; ++s) {
    // wait for step-s's 3 loads; keep later steps' loads in flight
    if (s + 2 < NSTEP)
      asm volatile("s_waitcnt vmcnt(6)" ::: "memory");
    else if (s + 1 < NSTEP)
      asm volatile("s_waitcnt vmcnt(3)" ::: "memory");
    else
      asm volatile("s_waitcnt vmcnt(0)" ::: "memory");
    asm volatile("s_waitcnt lgkmcnt(0)" ::: "memory");  // prev step's ds_reads done
    __builtin_amdgcn_sched_barrier(0);
    __builtin_amdgcn_s_barrier();
    __builtin_amdgcn_sched_barrier(0);

    if (s + 3 < NSTEP) STAGE(s + 3);  // issue-early; overwrites buf[(s-1)&3]

    const char* wb = Wb0 + (s & 3) * 8192;
    const char* xl = Xb0 + (s & 3) * 4096;
    f32x4 w0 = *(const f32x4*)(wb + bofs0);
    f32x4 w1 = *(const f32x4*)(wb + bofs1);
    s16x8 bfr = cvt8(w0, w1);
#pragma unroll
    for (int g = 0; g < 4; ++g) {
      s16x8 a = *(const s16x8*)(xl + aofs + g * 256);
      acc[g] = __builtin_amdgcn_mfma_f32_16x16x32_bf16(a, bfr, acc[g], 0, 0, 0);
    }
  }
#undef STAGE

  // C/D: i = i0 + rB (col = lane&15 within wave's 16 rows), b = g*16 + q*4 + j
  float* hp = ht + (size_t)(i0 + rB) * BATCH + q * 4;
#pragma unroll
  for (int g = 0; g < 4; ++g)
#pragma unroll
    for (int j = 0; j < 4; ++j)
      atomicAdd(hp + g * 16 + j, acc[g][j]);
}

// out_t[c][b] += ht[r][b] * w  for each nnz. One wave per nnz-chunk, lane = b.
__global__ void k_scatter(const float* __restrict__ ht, const float* __restrict__ sw,
                          const int* __restrict__ rows, const int* __restrict__ cols,
                          float* __restrict__ out_t) {
  const int w = (blockIdx.x * 256 + threadIdx.x) >> 6;  // 0..4095
  const int lane = threadIdx.x & 63;
  const int n0 = w * (NNZT / 4096);                     // 64 nnz per wave
#pragma unroll 4
  for (int n = n0; n < n0 + (NNZT / 4096); ++n) {
    const int r = rows[n];
    const int c = cols[n];
    const float wv = sw[n];
    atomicAdd(out_t + (size_t)c * BATCH + lane, ht[(size_t)r * BATCH + lane] * wv);
  }
}

// out[b][j] = leaky(out_t[j][b]) via LDS transpose. Grid 128 (j-tiles of 64).
__global__ void k_final(const float* __restrict__ out_t, float* __restrict__ out) {
  __shared__ float tile[64][65];
  const int t = threadIdx.x;
  const int j0 = blockIdx.x * 64;
  {
    const int jl = t >> 2, b0 = (t & 3) * 16;
    const float* src = out_t + (size_t)(j0 + jl) * BATCH + b0;
#pragma unroll
    for (int e = 0; e < 16; e += 4) {
      float4 v = *reinterpret_cast<const float4*>(src + e);
      tile[jl][b0 + e + 0] = v.x;
      tile[jl][b0 + e + 1] = v.y;
      tile[jl][b0 + e + 2] = v.z;
      tile[jl][b0 + e + 3] = v.w;
    }
  }
  __syncthreads();
  {
    const int bl = t >> 2, js = (t & 3) * 16;
    float* dst = out + (size_t)bl * NE + j0 + js;
#pragma unroll
    for (int e = 0; e < 16; e += 4) {
      float a0 = tile[js + e + 0][bl];
      float a1 = tile[js + e + 1][bl];
      float a2 = tile[js + e + 2][bl];
      float a3 = tile[js + e + 3][bl];
      float4 v;
      v.x = a0 >= 0.f ? a0 : 0.001f * a0;
      v.y = a1 >= 0.f ? a1 : 0.001f * a1;
      v.z = a2 >= 0.f ? a2 : 0.001f * a2;
      v.w = a3 >= 0.f ? a3 : 0.001f * a3;
      *reinterpret_cast<float4*>(dst + e) = v;
    }
  }
}

extern "C" void kernel_launch(void* const* d_in, const int* in_sizes, int n_in,
                              void* d_out, int out_size, void* d_ws, size_t ws_size,
                              hipStream_t stream) {
  const float* x = (const float*)d_in[0];
  const float* W = (const float*)d_in[1];
  const float* sw = (const float*)d_in[2];
  const int* idx = (const int*)d_in[3];  // [2][NNZ]: rows then cols
  float* out = (float*)d_out;

  char* ws = (char*)d_ws;
  float* ht = (float*)ws;                                   // 2 MB: ht[8192][64]
  float* out_t = (float*)(ws + (2 << 20));                  // 2 MB: out_t[8192][64]
  unsigned short* xbf = (unsigned short*)(ws + (4 << 20));  // 1 MB: x in bf16

  k_convert_x<<<512, 256, 0, stream>>>(x, xbf);
  k_zero<<<1024, 256, 0, stream>>>((float*)ws);  // zero ht + out_t (4 MB)
  k_dense<<<1024, 256, 0, stream>>>(xbf, W, ht);
  k_scatter<<<1024, 256, 0, stream>>>(ht, sw, idx, idx + NNZT, out_t);
  k_final<<<128, 256, 0, stream>>>(out_t, out);
}